// Round 1
// baseline (3548.957 us; speedup 1.0000x reference)
//
#include <hip/hip_runtime.h>
#include <cstdint>
#include <cstddef>

#define NS    8192
#define HDIM  1024
#define B0DIM 64
#define FDIM  2048
#define ODIM  2048
#define NBLK  6
#define XCOLS (HDIM + B0DIM + FDIM)   // 3136
#define SBW   (HDIM + B0DIM)          // 1088 (s+h0 concat width)

typedef __bf16 bf16_t;
typedef __bf16 bf16x8 __attribute__((ext_vector_type(8)));
typedef float  f32x4  __attribute__((ext_vector_type(4)));

__device__ inline bf16x8 cvt8(f32x4 lo, f32x4 hi) {
  bf16x8 r;
#pragma unroll
  for (int i = 0; i < 4; ++i) { r[i] = (bf16_t)lo[i]; r[i + 4] = (bf16_t)hi[i]; }
  return r;
}

// async global->LDS, 16B per lane; lds dest = wave-uniform base + lane*16
__device__ __forceinline__ void gload16(bf16_t* lds, const bf16_t* g) {
  __builtin_amdgcn_global_load_lds(
      (const __attribute__((address_space(1))) unsigned int*)g,
      (__attribute__((address_space(3))) unsigned int*)lds, 16, 0, 0);
}

// ------------------------------------------------------------------
// prep: one pass over x. xbf = bf16(x[:, :1088]) (s,h0 concat, lda 1088),
// dbf = bf16(d), q = bf16(pi/4 * round(d)^2)  (same rounding as verified ew_qinit)
// ------------------------------------------------------------------
__global__ __launch_bounds__(256) void prep(const float* __restrict__ x,
                                            bf16_t* __restrict__ xbf,
                                            bf16_t* __restrict__ dbf,
                                            bf16_t* __restrict__ qo) {
  int t = blockIdx.x * 256 + threadIdx.x;   // NS*392 threads (392 chunks/row)
  int n = t / 392;
  int c = t - n * 392;
  const float* p = x + (size_t)n * XCOLS + c * 8;
  f32x4 lo = *(const f32x4*)p;
  f32x4 hi = *(const f32x4*)(p + 4);
  if (c < 136) {
    *(bf16x8*)(xbf + (size_t)n * SBW + c * 8) = cvt8(lo, hi);
  } else {
    int j = c * 8 - SBW;
    bf16x8 od, oq;
#pragma unroll
    for (int i = 0; i < 4; ++i) {
      bf16_t b0 = (bf16_t)lo[i], b1 = (bf16_t)hi[i];
      od[i] = b0; od[i + 4] = b1;
      float f0 = (float)b0, f1 = (float)b1;
      oq[i]     = (bf16_t)(0.7853981633974483f * f0 * f0);
      oq[i + 4] = (bf16_t)(0.7853981633974483f * f1 * f1);
    }
    *(bf16x8*)(dbf + (size_t)n * FDIM + j) = od;
    *(bf16x8*)(qo  + (size_t)n * FDIM + j) = oq;
  }
}

// ------------------------------------------------------------------
// up-to-4-region fp32 -> bf16 weight converter. counts in 8-elem units.
// ------------------------------------------------------------------
__global__ __launch_bounds__(256) void wconv4(
    const float* __restrict__ s0, bf16_t* __restrict__ d0, int n0,
    const float* __restrict__ s1, bf16_t* __restrict__ d1, int n1,
    const float* __restrict__ s2, bf16_t* __restrict__ d2, int n2,
    const float* __restrict__ s3, bf16_t* __restrict__ d3, int n3) {
  int t = blockIdx.x * 256 + threadIdx.x;
  const float* s; bf16_t* d;
  if (t < n0) { s = s0 + (size_t)t * 8; d = d0 + (size_t)t * 8; }
  else {
    t -= n0;
    if (t < n1) { s = s1 + (size_t)t * 8; d = d1 + (size_t)t * 8; }
    else {
      t -= n1;
      if (t < n2) { s = s2 + (size_t)t * 8; d = d2 + (size_t)t * 8; }
      else {
        t -= n2;
        if (t < n3) { s = s3 + (size_t)t * 8; d = d3 + (size_t)t * 8; }
        else return;
      }
    }
  }
  f32x4 lo = *(const f32x4*)s, hi = *(const f32x4*)(s + 4);
  *(bf16x8*)d = cvt8(lo, hi);
}

// ------------------------------------------------------------------
// NT GEMM, all-bf16 operands, global_load_lds staging (m97 structure).
// C[n][m] = epi( sum_k A[n][k]*W[m][k] + bias[m] )
// 128x128 tile, 4 waves, 4x4 x mfma_f32_16x16x32_bf16 per wave.
// EPI: 0 none          C=(bf16)v
//      1 relu          C=(bf16)relu(v)
//      7 accum         C=(bf16)(v + C)
//      2 resS: r=relu(v); C=r; out2 = r * p1            (p1=q)
//      3 Aq:   a=v;      C=a; out2 = a * (p1 + p2)      (p1=q, p2=sumq)
//      4 fh/u: h=relu(v); C = (h + p1 + p2) * C         (C=tH1 holds D_h; RMW)
//      5 qupd: z=leaky(v,alpha); qn = C - z; C=qn; out2 = qn * p1   (p1=resS)
//      6 f32 out: Cf = v
// ------------------------------------------------------------------
template <int EPI>
__global__ __launch_bounds__(256) void gemm_bt(
    const bf16_t* __restrict__ A, int lda, const bf16_t* __restrict__ W, int K,
    const float* __restrict__ bias, bf16_t* __restrict__ C, int ldc,
    float* __restrict__ Cf, bf16_t* __restrict__ out2,
    const bf16_t* __restrict__ p1, const bf16_t* __restrict__ p2,
    const float* __restrict__ alpha_p) {
  __shared__ __align__(16) bf16_t As[128 * 32];
  __shared__ __align__(16) bf16_t Bs[128 * 32];

  const int tid  = threadIdx.x;
  const int lane = tid & 63;
  const int wave = tid >> 6;
  const int wm   = wave & 1;
  const int wn   = wave >> 1;
  const int row0 = blockIdx.y * 128;
  const int col0 = blockIdx.x * 128;

  // staging: wave w covers rows [w*32, w*32+32); lane l -> row +(l>>2), chunk (l&3)*8
  const int srow = wave * 32 + (lane >> 2);
  const int scol = (lane & 3) * 8;
  const bf16_t* ga0 = A + (size_t)(row0 + srow) * lda + scol;
  const bf16_t* ga1 = ga0 + (size_t)16 * lda;
  const bf16_t* gb0 = W + (size_t)(col0 + srow) * K + scol;
  const bf16_t* gb1 = gb0 + (size_t)16 * K;
  bf16_t* la0 = &As[(wave * 32) * 32];        // wave-uniform LDS bases
  bf16_t* la1 = &As[(wave * 32 + 16) * 32];
  bf16_t* lb0 = &Bs[(wave * 32) * 32];
  bf16_t* lb1 = &Bs[(wave * 32 + 16) * 32];

  f32x4 acc[4][4];
#pragma unroll
  for (int i = 0; i < 4; ++i)
#pragma unroll
    for (int j = 0; j < 4; ++j)
#pragma unroll
      for (int r = 0; r < 4; ++r) acc[i][j][r] = 0.0f;

  const int fr   = lane & 15;
  const int quad = lane >> 4;
  const int nk   = K >> 5;

  for (int kt = 0; kt < nk; ++kt) {
    const int ko = kt * 32;
    __syncthreads();
    gload16(la0, ga0 + ko);
    gload16(la1, ga1 + ko);
    gload16(lb0, gb0 + ko);
    gload16(lb1, gb1 + ko);
    __syncthreads();   // compiler drains vmcnt(0) before s_barrier

    bf16x8 af[4], bfr[4];
#pragma unroll
    for (int mt = 0; mt < 4; ++mt)
      af[mt] = *(const bf16x8*)&As[(wm * 64 + mt * 16 + fr) * 32 + quad * 8];
#pragma unroll
    for (int nt = 0; nt < 4; ++nt)
      bfr[nt] = *(const bf16x8*)&Bs[(wn * 64 + nt * 16 + fr) * 32 + quad * 8];
#pragma unroll
    for (int mt = 0; mt < 4; ++mt)
#pragma unroll
      for (int nt = 0; nt < 4; ++nt)
        acc[mt][nt] = __builtin_amdgcn_mfma_f32_16x16x32_bf16(
            af[mt], bfr[nt], acc[mt][nt], 0, 0, 0);
  }

  float alpha = 0.0f;
  if (EPI == 5) alpha = (float)(bf16_t)alpha_p[0];

#pragma unroll
  for (int mt = 0; mt < 4; ++mt) {
#pragma unroll
    for (int nt = 0; nt < 4; ++nt) {
      int ccol = col0 + wn * 64 + nt * 16 + fr;
      float bv = (float)(bf16_t)bias[ccol];
#pragma unroll
      for (int r = 0; r < 4; ++r) {
        int crow = row0 + wm * 64 + mt * 16 + quad * 4 + r;
        size_t idx = (size_t)crow * ldc + ccol;
        float v = acc[mt][nt][r] + bv;
        if (EPI == 0) C[idx] = (bf16_t)v;
        if (EPI == 1) C[idx] = (bf16_t)(v > 0.0f ? v : 0.0f);
        if (EPI == 7) { v += (float)C[idx]; C[idx] = (bf16_t)v; }
        if (EPI == 2) {
          bf16_t rb = (bf16_t)(v > 0.0f ? v : 0.0f);
          C[idx] = rb;
          out2[idx] = (bf16_t)((float)rb * (float)p1[idx]);
        }
        if (EPI == 3) {
          bf16_t ab = (bf16_t)v;
          C[idx] = ab;
          out2[idx] = (bf16_t)((float)ab * ((float)p1[idx] + (float)p2[idx]));
        }
        if (EPI == 4) {
          bf16_t hb = (bf16_t)(v > 0.0f ? v : 0.0f);
          float dh = (float)C[idx];   // D_h (RMW through same pointer)
          C[idx] = (bf16_t)(((float)hb + (float)p1[idx] + (float)p2[idx]) * dh);
        }
        if (EPI == 5) {
          float z = v >= 0.0f ? v : alpha * v;
          bf16_t qn = (bf16_t)((float)C[idx] - z);
          C[idx] = qn;
          out2[idx] = (bf16_t)((float)qn * (float)p1[idx]);
        }
        if (EPI == 6) Cf[idx] = v;
      }
    }
  }
}

template <int EPI>
static inline void launch_gemm(const bf16_t* A, int lda, const bf16_t* W, int K,
                               const float* bias, void* C, int M, bf16_t* out2,
                               const bf16_t* p1, const bf16_t* p2,
                               const float* alpha, hipStream_t s) {
  dim3 grid(M / 128, NS / 128), blk(256);
  gemm_bt<EPI><<<grid, blk, 0, s>>>(A, lda, W, K, bias, (bf16_t*)C, M,
                                    (float*)C, out2, p1, p2, alpha);
}

extern "C" void kernel_launch(void* const* d_in, const int* in_sizes, int n_in,
                              void* d_out, int out_size, void* d_ws,
                              size_t ws_size, hipStream_t stream) {
  const float* x      = (const float*)d_in[0];
  const float* W_h0q  = (const float*)d_in[1];
  const float* b_h0q  = (const float*)d_in[2];
  const float* W_sq   = (const float*)d_in[3];
  const float* b_sq   = (const float*)d_in[4];
  const float* W_h0h  = (const float*)d_in[5];
  const float* b_h0h  = (const float*)d_in[6];
  const float* W_S    = (const float*)d_in[7];
  const float* b_S    = (const float*)d_in[8];
  const float* W_q0h  = (const float*)d_in[9];
  const float* b_q0h  = (const float*)d_in[10];
  const float* Wb_Aq  = (const float*)d_in[11];
  const float* bb_Aq  = (const float*)d_in[12];
  const float* Wb_Dh  = (const float*)d_in[13];
  const float* bb_Dh  = (const float*)d_in[14];
  const float* Wb_fh  = (const float*)d_in[15];
  const float* bb_fh  = (const float*)d_in[16];
  const float* Wb_hf  = (const float*)d_in[17];
  const float* bb_hf  = (const float*)d_in[18];
  const float* a_hf   = (const float*)d_in[19];
  const float* Wb_rq  = (const float*)d_in[20];
  const float* bb_rq  = (const float*)d_in[21];
  const float* W_out  = (const float*)d_in[22];
  const float* b_out  = (const float*)d_in[23];

  const size_t NFb = (size_t)NS * FDIM * sizeof(bf16_t);  // 33.5 MB
  const size_t NHb = (size_t)NS * HDIM * sizeof(bf16_t);  // 16.8 MB
  if (ws_size < 4 * NFb + 4 * NHb) return;   // same footprint as verified kernel

  char* ws = (char*)d_ws;
  bf16_t* q     = (bf16_t*)(ws);
  bf16_t* resS  = (bf16_t*)(ws + NFb);
  bf16_t* sumq  = (bf16_t*)(ws + 2 * NFb);   // prologue: also holds dbf
  bf16_t* tF1   = (bf16_t*)(ws + 3 * NFb);   // q*resS feed for Aq GEMM
  bf16_t* resqh = (bf16_t*)(ws + 4 * NFb);
  bf16_t* sumh  = (bf16_t*)(ws + 4 * NFb + NHb);
  bf16_t* tH1   = (bf16_t*)(ws + 4 * NFb + 2 * NHb);  // D_h, then u (in-place)
  bf16_t* WS    = (bf16_t*)(ws + 4 * NFb + 3 * NHb);  // 16.8MB bf16 weight slot
  bf16_t* xbf   = tH1;            // prologue only: 8192x1088 (spills 1MB into WS)
  bf16_t* dbf   = sumq;           // prologue only
  bf16_t* AqB   = (bf16_t*)d_out;                       // d_out lower half
  bf16_t* dW    = (bf16_t*)d_out + (size_t)NS * FDIM;   // d_out upper half:
  bf16_t* tFh   = dW;             // prologue = weight region; block loop = hid

  // region sizes in 8-elem units
  const int uFF = FDIM * FDIM / 8;   // 524288 (2048x2048)
  const int uHF = HDIM * FDIM / 8;   // 262144 (1024x2048)
  const int uQ0 = FDIM * B0DIM / 8;  // 16384
  const int uH0 = HDIM * B0DIM / 8;  // 8192

  // ---- prologue ----
  prep<<<NS * 392 / 256, 256, 0, stream>>>(x, xbf, dbf, q);

  wconv4<<<(uFF + 255) / 256, 256, 0, stream>>>(
      W_S, dW, uFF, nullptr, nullptr, 0, nullptr, nullptr, 0, nullptr, nullptr, 0);
  // res_S_q = relu(d @ W_S^T + b_S); fused: tF1 = resS * q
  launch_gemm<2>(dbf, FDIM, dW, FDIM, b_S, resS, FDIM, tF1, q, nullptr, nullptr, stream);

  // convert remaining prologue weights (overwrites W_S region; serial stream)
  bf16_t* dWsq = dW;
  bf16_t* dWhq = dW + (size_t)uFF * 0 + (size_t)FDIM * HDIM;        // +2,097,152
  bf16_t* dWhh = dWhq + (size_t)FDIM * B0DIM;                       // +131,072
  bf16_t* dWqh = dWhh + (size_t)HDIM * B0DIM;                       // +65,536
  wconv4<<<(uHF + uQ0 + uH0 + uHF + 255) / 256, 256, 0, stream>>>(
      W_sq, dWsq, uHF, W_h0q, dWhq, uQ0, W_h0h, dWhh, uH0, W_q0h, dWqh, uHF);

  // sum_q_const = s @ W_sq^T + b_sq  (overwrites dbf: safe, serial)
  launch_gemm<0>(xbf, SBW, dWsq, HDIM, b_sq, sumq, FDIM, nullptr, nullptr, nullptr, nullptr, stream);
  // sum_q_const += h0 @ W_h0q^T + b_h0q
  launch_gemm<7>(xbf + HDIM, SBW, dWhq, B0DIM, b_h0q, sumq, FDIM, nullptr, nullptr, nullptr, nullptr, stream);
  // sum_h_const = h0 @ W_h0h^T + b_h0h
  launch_gemm<0>(xbf + HDIM, SBW, dWhh, B0DIM, b_h0h, sumh, HDIM, nullptr, nullptr, nullptr, nullptr, stream);
  // res_q_h = q @ W_q0h^T + b_q0h  (no relu on initial)
  launch_gemm<0>(q, FDIM, dWqh, FDIM, b_q0h, resqh, HDIM, nullptr, nullptr, nullptr, nullptr, stream);

  // weight-slot offsets (elems)
  bf16_t* wA = WS;                            // 2048x2048
  bf16_t* wD = WS + (size_t)FDIM * FDIM;      // 1024x2048
  bf16_t* wF = WS;                            // 1024x2048 (phase 2)
  bf16_t* wH = WS + (size_t)HDIM * FDIM;      // 2048x1024
  bf16_t* wR = WS + 2 * (size_t)HDIM * FDIM;  // 1024x2048

  // ---- block loop ----
  for (int b = 0; b < NBLK; ++b) {
    const float* c_Aq = bb_Aq + (size_t)b * FDIM;
    const float* c_Dh = bb_Dh + (size_t)b * HDIM;
    const float* c_fh = bb_fh + (size_t)b * HDIM;
    const float* c_hf = bb_hf + (size_t)b * FDIM;
    const float* c_r  = bb_rq + (size_t)b * HDIM;

    wconv4<<<(uFF + uHF + 255) / 256, 256, 0, stream>>>(
        Wb_Aq + (size_t)b * FDIM * FDIM, wA, uFF,
        Wb_Dh + (size_t)b * HDIM * FDIM, wD, uHF,
        nullptr, nullptr, 0, nullptr, nullptr, 0);
    // A_q = tF1 @ W_Aq^T + b_Aq ; fused: hid(tFh) = A_q * (q + sumq)
    launch_gemm<3>(tF1, FDIM, wA, FDIM, c_Aq, AqB, FDIM, tFh, q, sumq, nullptr, stream);
    // D_h = relu(A_q @ W_Dh^T + b_Dh)
    launch_gemm<1>(AqB, FDIM, wD, FDIM, c_Dh, tH1, HDIM, nullptr, nullptr, nullptr, nullptr, stream);

    wconv4<<<(3 * uHF + 255) / 256, 256, 0, stream>>>(
        Wb_fh + (size_t)b * HDIM * FDIM, wF, uHF,
        Wb_hf + (size_t)b * FDIM * HDIM, wH, uHF,
        Wb_rq + (size_t)b * HDIM * FDIM, wR, uHF,
        nullptr, nullptr, 0);
    // h = relu(hid @ W_fh^T + b_fh); fused: tH1 = (h + sumh + resqh) * D_h
    launch_gemm<4>(tFh, FDIM, wF, FDIM, c_fh, tH1, HDIM, nullptr, sumh, resqh, nullptr, stream);
    // q = q - leaky(u @ W_hf^T + b_hf, a[b]); fused: tF1 = qnew * resS
    launch_gemm<5>(tH1, HDIM, wH, HDIM, c_hf, q, FDIM, tF1, resS, nullptr, a_hf + b, stream);
    // res_q_h = relu(q @ W_resq^T + b_resq)
    launch_gemm<1>(q, FDIM, wR, FDIM, c_r, resqh, HDIM, nullptr, nullptr, nullptr, nullptr, stream);
  }

  // ---- output ----
  wconv4<<<(uFF + 255) / 256, 256, 0, stream>>>(
      W_out, WS, uFF, nullptr, nullptr, 0, nullptr, nullptr, 0, nullptr, nullptr, 0);
  launch_gemm<6>(q, FDIM, WS, FDIM, b_out, d_out, ODIM, nullptr, nullptr, nullptr, nullptr, stream);
}

// Round 3
// 2943.498 us; speedup vs baseline: 1.2057x; 1.2057x over previous
//
#include <hip/hip_runtime.h>
#include <cstdint>
#include <cstddef>

#define NS    8192
#define HDIM  1024
#define B0DIM 64
#define FDIM  2048
#define ODIM  2048
#define NBLK  6
#define XCOLS (HDIM + B0DIM + FDIM)   // 3136
#define SBW   (HDIM + B0DIM)          // 1088 (s+h0 concat width)

typedef __bf16 bf16_t;
typedef __bf16 bf16x8 __attribute__((ext_vector_type(8)));
typedef float  f32x4  __attribute__((ext_vector_type(4)));

__device__ inline bf16x8 cvt8(f32x4 lo, f32x4 hi) {
  bf16x8 r;
#pragma unroll
  for (int i = 0; i < 4; ++i) { r[i] = (bf16_t)lo[i]; r[i + 4] = (bf16_t)hi[i]; }
  return r;
}

// async global->LDS, 16B per lane; lds dest = wave-uniform base + lane*16
__device__ __forceinline__ void gload16(bf16_t* lds, const bf16_t* g) {
  __builtin_amdgcn_global_load_lds(
      (const __attribute__((address_space(1))) unsigned int*)g,
      (__attribute__((address_space(3))) unsigned int*)lds, 16, 0, 0);
}

// ------------------------------------------------------------------
// prep: one pass over x. xbf = bf16(x[:, :1088]) (s,h0 concat, lda 1088),
// dbf = bf16(d), q = bf16(pi/4 * round(d)^2)
// ------------------------------------------------------------------
__global__ __launch_bounds__(256) void prep(const float* __restrict__ x,
                                            bf16_t* __restrict__ xbf,
                                            bf16_t* __restrict__ dbf,
                                            bf16_t* __restrict__ qo) {
  int t = blockIdx.x * 256 + threadIdx.x;   // NS*392 threads (392 chunks/row)
  int n = t / 392;
  int c = t - n * 392;
  const float* p = x + (size_t)n * XCOLS + c * 8;
  f32x4 lo = *(const f32x4*)p;
  f32x4 hi = *(const f32x4*)(p + 4);
  if (c < 136) {
    *(bf16x8*)(xbf + (size_t)n * SBW + c * 8) = cvt8(lo, hi);
  } else {
    int j = c * 8 - SBW;
    bf16x8 od, oq;
#pragma unroll
    for (int i = 0; i < 4; ++i) {
      bf16_t b0 = (bf16_t)lo[i], b1 = (bf16_t)hi[i];
      od[i] = b0; od[i + 4] = b1;
      float f0 = (float)b0, f1 = (float)b1;
      oq[i]     = (bf16_t)(0.7853981633974483f * f0 * f0);
      oq[i + 4] = (bf16_t)(0.7853981633974483f * f1 * f1);
    }
    *(bf16x8*)(dbf + (size_t)n * FDIM + j) = od;
    *(bf16x8*)(qo  + (size_t)n * FDIM + j) = oq;
  }
}

// ------------------------------------------------------------------
// up-to-4-region fp32 -> bf16 weight converter. counts in 8-elem units.
// ------------------------------------------------------------------
__global__ __launch_bounds__(256) void wconv4(
    const float* __restrict__ s0, bf16_t* __restrict__ d0, int n0,
    const float* __restrict__ s1, bf16_t* __restrict__ d1, int n1,
    const float* __restrict__ s2, bf16_t* __restrict__ d2, int n2,
    const float* __restrict__ s3, bf16_t* __restrict__ d3, int n3) {
  int t = blockIdx.x * 256 + threadIdx.x;
  const float* s; bf16_t* d;
  if (t < n0) { s = s0 + (size_t)t * 8; d = d0 + (size_t)t * 8; }
  else {
    t -= n0;
    if (t < n1) { s = s1 + (size_t)t * 8; d = d1 + (size_t)t * 8; }
    else {
      t -= n1;
      if (t < n2) { s = s2 + (size_t)t * 8; d = d2 + (size_t)t * 8; }
      else {
        t -= n2;
        if (t < n3) { s = s3 + (size_t)t * 8; d = d3 + (size_t)t * 8; }
        else return;
      }
    }
  }
  f32x4 lo = *(const f32x4*)s, hi = *(const f32x4*)(s + 4);
  *(bf16x8*)d = cvt8(lo, hi);
}

// ------------------------------------------------------------------
// NT GEMM, all-bf16, global_load_lds staging, 3-buffer depth-2 pipeline
// with counted vmcnt (T3+T4), XCD-aware block swizzle (T1).
// C[n][m] = epi( sum_k A[n][k]*W[m][k] + b[m] )
// 128x128 tile, 4 waves, 4x4 x mfma_f32_16x16x32_bf16 per wave.
// EPI: 0 none; 1 relu; 7 accum; 2 resS(relu,out2=r*p1); 3 Aq(out2=a*(p1+p2));
//      4 fh/u(C=(relu(v)+p1+p2)*C); 5 qupd(qn=C-leaky; out2=qn*p1); 6 f32 out
// ------------------------------------------------------------------
template <int EPI>
__global__ __launch_bounds__(256) void gemm_bt(
    const bf16_t* __restrict__ A, int lda, const bf16_t* __restrict__ W, int K,
    const float* __restrict__ bias, bf16_t* __restrict__ C, int ldc,
    float* __restrict__ Cf, bf16_t* __restrict__ out2,
    const bf16_t* __restrict__ p1, const bf16_t* __restrict__ p2,
    const float* __restrict__ alpha_p) {
  __shared__ __align__(16) bf16_t As[3][128 * 32];
  __shared__ __align__(16) bf16_t Bs[3][128 * 32];

  const int tid  = threadIdx.x;
  const int lane = tid & 63;
  const int wave = tid >> 6;
  const int wm   = wave & 1;
  const int wn   = wave >> 1;

  // XCD-aware swizzle: grids here always have (gx*gy) % 8 == 0 -> bijective.
  const int gx  = gridDim.x;
  const int bid = blockIdx.y * gx + blockIdx.x;
  const int cpx = (gx * gridDim.y) >> 3;
  const int swz = (bid & 7) * cpx + (bid >> 3);
  const int row0 = (swz / gx) * 128;
  const int col0 = (swz % gx) * 128;

  // staging: wave w covers rows [w*32, w*32+32); lane l -> row +(l>>2), chunk (l&3)*8
  const int srow = wave * 32 + (lane >> 2);
  const int scol = (lane & 3) * 8;
  const bf16_t* ga0 = A + (size_t)(row0 + srow) * lda + scol;
  const bf16_t* ga1 = ga0 + (size_t)16 * lda;
  const bf16_t* gb0 = W + (size_t)(col0 + srow) * K + scol;
  const bf16_t* gb1 = gb0 + (size_t)16 * K;
  const int lofs0 = (wave * 32) * 32;        // wave-uniform LDS elem offsets
  const int lofs1 = (wave * 32 + 16) * 32;

  f32x4 acc[4][4];
#pragma unroll
  for (int i = 0; i < 4; ++i)
#pragma unroll
    for (int j = 0; j < 4; ++j)
#pragma unroll
      for (int r = 0; r < 4; ++r) acc[i][j][r] = 0.0f;

  const int fr   = lane & 15;
  const int quad = lane >> 4;
  const int nk   = K >> 5;

  auto stage = [&](int buf, int ko) {
    gload16(&As[buf][lofs0], ga0 + ko);
    gload16(&As[buf][lofs1], ga1 + ko);
    gload16(&Bs[buf][lofs0], gb0 + ko);
    gload16(&Bs[buf][lofs1], gb1 + ko);
  };

  auto compute = [&](int buf) {
    bf16x8 af[4], bfr[4];
#pragma unroll
    for (int mt = 0; mt < 4; ++mt)
      af[mt] = *(const bf16x8*)&As[buf][(wm * 64 + mt * 16 + fr) * 32 + quad * 8];
#pragma unroll
    for (int nt = 0; nt < 4; ++nt)
      bfr[nt] = *(const bf16x8*)&Bs[buf][(wn * 64 + nt * 16 + fr) * 32 + quad * 8];
#pragma unroll
    for (int mt = 0; mt < 4; ++mt)
#pragma unroll
      for (int nt = 0; nt < 4; ++nt)
        acc[mt][nt] = __builtin_amdgcn_mfma_f32_16x16x32_bf16(
            af[mt], bfr[nt], acc[mt][nt], 0, 0, 0);
  };

  // prologue: prefetch tiles 0 and 1 (per-wave 8 outstanding vmem ops)
  stage(0, 0);
  if (nk > 1) stage(1, 32);

  int rd = 0, wr = 2;
  for (int kt = 0; kt < nk - 1; ++kt) {
    // tile kt landed (leave tile kt+1's 4 loads in flight; never drain to 0)
    asm volatile("s_waitcnt vmcnt(4)" ::: "memory");
    __builtin_amdgcn_s_barrier();   // all waves: tile kt visible; buf wr free
    if (kt + 2 < nk) stage(wr, (kt + 2) * 32);
    compute(rd);
    rd = (rd == 2) ? 0 : rd + 1;
    wr = (wr == 2) ? 0 : wr + 1;
  }
  asm volatile("s_waitcnt vmcnt(0)" ::: "memory");
  __builtin_amdgcn_s_barrier();
  compute(rd);

  float alpha = 0.0f;
  if (EPI == 5) alpha = (float)(bf16_t)alpha_p[0];

#pragma unroll
  for (int mt = 0; mt < 4; ++mt) {
#pragma unroll
    for (int nt = 0; nt < 4; ++nt) {
      int ccol = col0 + wn * 64 + nt * 16 + fr;
      float bv = (float)(bf16_t)bias[ccol];
#pragma unroll
      for (int r = 0; r < 4; ++r) {
        int crow = row0 + wm * 64 + mt * 16 + quad * 4 + r;
        size_t idx = (size_t)crow * ldc + ccol;
        float v = acc[mt][nt][r] + bv;
        if (EPI == 0) C[idx] = (bf16_t)v;
        if (EPI == 1) C[idx] = (bf16_t)(v > 0.0f ? v : 0.0f);
        if (EPI == 7) { v += (float)C[idx]; C[idx] = (bf16_t)v; }
        if (EPI == 2) {
          bf16_t rb = (bf16_t)(v > 0.0f ? v : 0.0f);
          C[idx] = rb;
          out2[idx] = (bf16_t)((float)rb * (float)p1[idx]);
        }
        if (EPI == 3) {
          bf16_t ab = (bf16_t)v;
          C[idx] = ab;
          out2[idx] = (bf16_t)((float)ab * ((float)p1[idx] + (float)p2[idx]));
        }
        if (EPI == 4) {
          bf16_t hb = (bf16_t)(v > 0.0f ? v : 0.0f);
          float dh = (float)C[idx];   // D_h (RMW through same pointer)
          C[idx] = (bf16_t)(((float)hb + (float)p1[idx] + (float)p2[idx]) * dh);
        }
        if (EPI == 5) {
          float z = v >= 0.0f ? v : alpha * v;
          bf16_t qn = (bf16_t)((float)C[idx] - z);
          C[idx] = qn;
          out2[idx] = (bf16_t)((float)qn * (float)p1[idx]);
        }
        if (EPI == 6) Cf[idx] = v;
      }
    }
  }
}

template <int EPI>
static inline void launch_gemm(const bf16_t* A, int lda, const bf16_t* W, int K,
                               const float* bias, void* C, int M, bf16_t* out2,
                               const bf16_t* p1, const bf16_t* p2,
                               const float* alpha, hipStream_t s) {
  dim3 grid(M / 128, NS / 128), blk(256);
  gemm_bt<EPI><<<grid, blk, 0, s>>>(A, lda, W, K, bias, (bf16_t*)C, M,
                                    (float*)C, out2, p1, p2, alpha);
}

extern "C" void kernel_launch(void* const* d_in, const int* in_sizes, int n_in,
                              void* d_out, int out_size, void* d_ws,
                              size_t ws_size, hipStream_t stream) {
  const float* x      = (const float*)d_in[0];
  const float* W_h0q  = (const float*)d_in[1];
  const float* b_h0q  = (const float*)d_in[2];
  const float* W_sq   = (const float*)d_in[3];
  const float* b_sq   = (const float*)d_in[4];
  const float* W_h0h  = (const float*)d_in[5];
  const float* b_h0h  = (const float*)d_in[6];
  const float* W_S    = (const float*)d_in[7];
  const float* b_S    = (const float*)d_in[8];
  const float* W_q0h  = (const float*)d_in[9];
  const float* b_q0h  = (const float*)d_in[10];
  const float* Wb_Aq  = (const float*)d_in[11];
  const float* bb_Aq  = (const float*)d_in[12];
  const float* Wb_Dh  = (const float*)d_in[13];
  const float* bb_Dh  = (const float*)d_in[14];
  const float* Wb_fh  = (const float*)d_in[15];
  const float* bb_fh  = (const float*)d_in[16];
  const float* Wb_hf  = (const float*)d_in[17];
  const float* bb_hf  = (const float*)d_in[18];
  const float* a_hf   = (const float*)d_in[19];
  const float* Wb_rq  = (const float*)d_in[20];
  const float* bb_rq  = (const float*)d_in[21];
  const float* W_out  = (const float*)d_in[22];
  const float* b_out  = (const float*)d_in[23];

  const size_t NFb = (size_t)NS * FDIM * sizeof(bf16_t);  // 33.5 MB
  const size_t NHb = (size_t)NS * HDIM * sizeof(bf16_t);  // 16.8 MB
  if (ws_size < 4 * NFb + 4 * NHb) return;

  char* ws = (char*)d_ws;
  bf16_t* q     = (bf16_t*)(ws);
  bf16_t* resS  = (bf16_t*)(ws + NFb);
  bf16_t* sumq  = (bf16_t*)(ws + 2 * NFb);   // prologue: also holds dbf
  bf16_t* tF1   = (bf16_t*)(ws + 3 * NFb);   // q*resS feed for Aq GEMM
  bf16_t* resqh = (bf16_t*)(ws + 4 * NFb);
  bf16_t* sumh  = (bf16_t*)(ws + 4 * NFb + NHb);
  bf16_t* tH1   = (bf16_t*)(ws + 4 * NFb + 2 * NHb);  // D_h, then u (in-place)
  bf16_t* WS    = (bf16_t*)(ws + 4 * NFb + 3 * NHb);  // 16.8MB bf16 weight slot
  bf16_t* xbf   = tH1;            // prologue only: 8192x1088 (spills into WS)
  bf16_t* dbf   = sumq;           // prologue only
  bf16_t* AqB   = (bf16_t*)d_out;                       // d_out lower half
  bf16_t* dW    = (bf16_t*)d_out + (size_t)NS * FDIM;   // d_out upper half
  bf16_t* tFh   = dW;             // prologue = weight region; block loop = hid

  const int uFF = FDIM * FDIM / 8;   // 524288
  const int uHF = HDIM * FDIM / 8;   // 262144
  const int uQ0 = FDIM * B0DIM / 8;  // 16384
  const int uH0 = HDIM * B0DIM / 8;  // 8192

  // ---- prologue ----
  prep<<<NS * 392 / 256, 256, 0, stream>>>(x, xbf, dbf, q);

  wconv4<<<(uFF + 255) / 256, 256, 0, stream>>>(
      W_S, dW, uFF, nullptr, nullptr, 0, nullptr, nullptr, 0, nullptr, nullptr, 0);
  // res_S_q = relu(d @ W_S^T + b_S); fused: tF1 = resS * q
  launch_gemm<2>(dbf, FDIM, dW, FDIM, b_S, resS, FDIM, tF1, q, nullptr, nullptr, stream);

  bf16_t* dWsq = dW;
  bf16_t* dWhq = dW + (size_t)FDIM * HDIM;
  bf16_t* dWhh = dWhq + (size_t)FDIM * B0DIM;
  bf16_t* dWqh = dWhh + (size_t)HDIM * B0DIM;
  wconv4<<<(uHF + uQ0 + uH0 + uHF + 255) / 256, 256, 0, stream>>>(
      W_sq, dWsq, uHF, W_h0q, dWhq, uQ0, W_h0h, dWhh, uH0, W_q0h, dWqh, uHF);

  launch_gemm<0>(xbf, SBW, dWsq, HDIM, b_sq, sumq, FDIM, nullptr, nullptr, nullptr, nullptr, stream);
  launch_gemm<7>(xbf + HDIM, SBW, dWhq, B0DIM, b_h0q, sumq, FDIM, nullptr, nullptr, nullptr, nullptr, stream);
  launch_gemm<0>(xbf + HDIM, SBW, dWhh, B0DIM, b_h0h, sumh, HDIM, nullptr, nullptr, nullptr, nullptr, stream);
  launch_gemm<0>(q, FDIM, dWqh, FDIM, b_q0h, resqh, HDIM, nullptr, nullptr, nullptr, nullptr, stream);

  bf16_t* wA = WS;
  bf16_t* wD = WS + (size_t)FDIM * FDIM;
  bf16_t* wF = WS;
  bf16_t* wH = WS + (size_t)HDIM * FDIM;
  bf16_t* wR = WS + 2 * (size_t)HDIM * FDIM;

  // ---- block loop ----
  for (int b = 0; b < NBLK; ++b) {
    const float* c_Aq = bb_Aq + (size_t)b * FDIM;
    const float* c_Dh = bb_Dh + (size_t)b * HDIM;
    const float* c_fh = bb_fh + (size_t)b * HDIM;
    const float* c_hf = bb_hf + (size_t)b * FDIM;
    const float* c_r  = bb_rq + (size_t)b * HDIM;

    wconv4<<<(uFF + uHF + 255) / 256, 256, 0, stream>>>(
        Wb_Aq + (size_t)b * FDIM * FDIM, wA, uFF,
        Wb_Dh + (size_t)b * HDIM * FDIM, wD, uHF,
        nullptr, nullptr, 0, nullptr, nullptr, 0);
    // A_q = tF1 @ W_Aq^T + b_Aq ; fused: hid(tFh) = A_q * (q + sumq)
    launch_gemm<3>(tF1, FDIM, wA, FDIM, c_Aq, AqB, FDIM, tFh, q, sumq, nullptr, stream);
    // D_h = relu(A_q @ W_Dh^T + b_Dh)
    launch_gemm<1>(AqB, FDIM, wD, FDIM, c_Dh, tH1, HDIM, nullptr, nullptr, nullptr, nullptr, stream);

    wconv4<<<(3 * uHF + 255) / 256, 256, 0, stream>>>(
        Wb_fh + (size_t)b * HDIM * FDIM, wF, uHF,
        Wb_hf + (size_t)b * FDIM * HDIM, wH, uHF,
        Wb_rq + (size_t)b * HDIM * FDIM, wR, uHF,
        nullptr, nullptr, 0);
    // h = relu(hid @ W_fh^T + b_fh); fused: tH1 = (h + sumh + resqh) * D_h
    launch_gemm<4>(tFh, FDIM, wF, FDIM, c_fh, tH1, HDIM, nullptr, sumh, resqh, nullptr, stream);
    // q = q - leaky(u @ W_hf^T + b_hf, a[b]); fused: tF1 = qnew * resS
    launch_gemm<5>(tH1, HDIM, wH, HDIM, c_hf, q, FDIM, tF1, resS, nullptr, a_hf + b, stream);
    // res_q_h = relu(q @ W_resq^T + b_resq)
    launch_gemm<1>(q, FDIM, wR, FDIM, c_r, resqh, HDIM, nullptr, nullptr, nullptr, nullptr, stream);
  }

  // ---- output ----
  wconv4<<<(uFF + 255) / 256, 256, 0, stream>>>(
      W_out, WS, uFF, nullptr, nullptr, 0, nullptr, nullptr, 0, nullptr, nullptr, 0);
  launch_gemm<6>(q, FDIM, WS, FDIM, b_out, d_out, ODIM, nullptr, nullptr, nullptr, nullptr, stream);
}